// Round 12
// baseline (741.679 us; speedup 1.0000x reference)
//
#include <hip/hip_runtime.h>
#include <hip/hip_bf16.h>

#define N_NODES 32768
#define NK      1048576      // N*K edges

typedef __bf16 bf16x8 __attribute__((ext_vector_type(8)));
typedef float  f32x4  __attribute__((ext_vector_type(4)));
typedef short  short8v __attribute__((ext_vector_type(8)));
typedef int    int4v  __attribute__((ext_vector_type(4)));

#define WAIT_LGKM() asm volatile("s_waitcnt lgkmcnt(0)" ::: "memory")

static __device__ __forceinline__ unsigned fbits(float f) {
    union { float f; unsigned u; } v; v.f = f; return v.u;
}
static __device__ __forceinline__ unsigned short f2bf(float f) {
    unsigned u = fbits(f);
    return (unsigned short)((u + 0x7fffu + ((u >> 16) & 1u)) >> 16);   // RNE (prep only)
}
static __device__ __forceinline__ unsigned short hwbf(float f) {      // HW RNE convert
    return __builtin_bit_cast(unsigned short, __float2bfloat16(f));
}

// DPP butterfly add over the 16-lane row (no DS pipe)
template<int CTRL>
static __device__ __forceinline__ float dpp_add(float v) {
    int sw = __builtin_amdgcn_update_dpp(0, __builtin_bit_cast(int, v), CTRL, 0xf, 0xf, true);
    return v + __builtin_bit_cast(float, sw);
}
static __device__ __forceinline__ float row16_sum(float v) {
    v = dpp_add<0xB1>(v);    // quad_perm(1,0,3,2)  : xor 1
    v = dpp_add<0x4E>(v);    // quad_perm(2,3,0,1)  : xor 2
    v = dpp_add<0x141>(v);   // row_half_mirror
    v = dpp_add<0x140>(v);   // row_mirror
    return v;
}

// R[a*3+b] = e_{b}[a]  (columns e1,e2,e3)
static __device__ __forceinline__ void make_frame(const float* __restrict__ p, float* __restrict__ R) {
    float v1x = p[6]-p[3], v1y = p[7]-p[4], v1z = p[8]-p[5];
    float v2x = p[0]-p[3], v2y = p[1]-p[4], v2z = p[2]-p[5];
    float i1 = 1.f/(sqrtf(v1x*v1x+v1y*v1y+v1z*v1z)+1e-6f);
    float e1x=v1x*i1, e1y=v1y*i1, e1z=v1z*i1;
    float dt = v2x*e1x+v2y*e1y+v2z*e1z;
    float u2x=v2x-dt*e1x, u2y=v2y-dt*e1y, u2z=v2z-dt*e1z;
    float i2 = 1.f/(sqrtf(u2x*u2x+u2y*u2y+u2z*u2z)+1e-6f);
    float e2x=u2x*i2, e2y=u2y*i2, e2z=u2z*i2;
    float e3x = e1y*e2z - e1z*e2y;
    float e3y = e1z*e2x - e1x*e2z;
    float e3z = e1x*e2y - e1y*e2x;
    R[0]=e1x; R[1]=e2x; R[2]=e3x;
    R[3]=e1y; R[4]=e2y; R[5]=e3y;
    R[6]=e1z; R[7]=e2z; R[8]=e3z;
}

// ---------------- prep: pack weights into frag-linear bf16 layouts (144 KB total) ----------------
// wftp: feature-GEMM B-frags, K=64. frag(pb,ks): f = 8*(lane>>4)+j+32*ks (<40 real, else 0),
//       p = pb*16+(lane&15).                                   [8192 shorts]
// w1p : GEMM1 A-frags, natural k=p. frag(ht,ks): h = ht*16+(lane&15),
//       p = 8*(lane>>4)+j+32*ks; value = W1[p][h].             [32768 shorts]
// w2p : GEMM2 B-frags with permuted k-carriage (matches gelu A-frag):
//       frag(pt,hc): h = hc*32 + (j>>2)*16 + 4*(lane>>4) + (j&3), p = pt*16+(lane&15);
//       value = W2[h][p].                                      [32768 shorts]
__global__ void sd_prep_weights(const float* __restrict__ W1, const float* __restrict__ W2,
                                const float* __restrict__ Wd, const float* __restrict__ Wdir,
                                const float* __restrict__ Wrot, const float* __restrict__ Wvec,
                                unsigned short* __restrict__ wftp, unsigned short* __restrict__ w1p,
                                unsigned short* __restrict__ w2p) {
    int i = blockIdx.x*256 + threadIdx.x;
    if (i < 8192) {
        int fragid = i >> 9, lane = (i >> 3) & 63, j = i & 7;
        int pb = fragid >> 1, ks = fragid & 1;
        int f = 8*(lane>>4) + j + 32*ks;
        int p = pb*16 + (lane & 15);
        float v = 0.f;
        if (f < 16)       v = Wd[f*128+p];
        else if (f < 19)  v = Wdir[(f-16)*128+p];
        else if (f < 28)  v = Wrot[(f-19)*128+p];
        else if (f < 40)  v = Wvec[(f-28)*128+p];
        wftp[i] = f2bf(v);
    } else if (i < 40960) {
        int idx = i - 8192;
        int fragid = idx >> 9, lane = (idx >> 3) & 63, j = idx & 7;
        int ht = fragid >> 2, ks = fragid & 3;
        int h = ht*16 + (lane & 15);
        int p = 8*(lane>>4) + j + 32*ks;          // natural order
        w1p[idx] = f2bf(W1[p*256 + h]);
    } else if (i < 73728) {
        int idx = i - 40960;
        int fragid = idx >> 9, lane = (idx >> 3) & 63, j = idx & 7;
        int pt = fragid >> 3, hc = fragid & 7;
        int h = hc*32 + (j>>2)*16 + 4*(lane>>4) + (j&3);
        int p = pt*16 + (lane & 15);
        w2p[idx] = f2bf(W2[h*128 + p]);
    }
}

__global__ void sd_mask_kernel(const int* __restrict__ nbr, const float* __restrict__ mask,
                               float* __restrict__ outm) {
    int g = blockIdx.x*256 + threadIdx.x;
    if (g >= NK) return;
    int j = nbr[g];
    int n = g >> 5;
    float pm = mask[n] * mask[j & (N_NODES-1)] * ((j != -1) ? 1.f : 0.f);
    outm[g] = pm;
}

#define MFMA32(a,b,c) __builtin_amdgcn_mfma_f32_16x16x32_bf16((a),(b),(c),0,0,0)

// 4 independent waves per block, 32 edges each. NO barriers anywhere.
// Per-wave LDS (8 KB, OVERLAPPED): feats [32 x 128B swz] = bytes 0..4095 of the region that
// X [32 x 256B swz] later fills (0..8191). SAFETY: a WAIT_LGKM (lgkmcnt(0) + "memory"
// clobber) sits between the last feats ds_read and the first X ds_write — all reads are
// COMPLETE before any write issues, and the compiler cannot reorder memory ops across it.
__global__ __launch_bounds__(256, 4) void sd_fused_kernel(
    const float* __restrict__ pos, const int* __restrict__ nbr,
    const int* __restrict__ resi, const int* __restrict__ chain,
    const int* __restrict__ batch, const float* __restrict__ W_rel,
    const float* __restrict__ ln_scale, const float* __restrict__ ln_bias,
    const float* __restrict__ b1, const float* __restrict__ b2,
    const char* __restrict__ wftp_c, const char* __restrict__ w1p_c,
    const char* __restrict__ w2p_c,
    float* __restrict__ out)
{
    __shared__ __align__(16) char smem[33280];
    const int t    = threadIdx.x;
    const int lane = t & 63;
    const int wid  = t >> 6;
    const int lrow = lane & 15;
    const int lk   = lane >> 4;
    const int edge0 = blockIdx.x * 128 + wid * 32;
    char* Fv = smem + wid * 8192;              // feats region (first 4 KB of wave region)
    char* Xv = Fv;                             // X region (full 8 KB, reuses feats space)
    int* meta = (int*)(smem + 32768 + wid*128);

    // ---- zero-fill feats region (tail f in [40,64) must be zero) ----
    {
        int4v z = (int4v){0,0,0,0};
        #pragma unroll
        for (int k = 0; k < 4; ++k) *(int4v*)(Fv + lane*64 + k*16) = z;
    }
    WAIT_LGKM();

    // ---- phase F: 2 lanes per edge (R8-proven scalar writes) ----
    {
        const int e   = lane >> 1;
        const int sub = lane & 1;
        const int g   = edge0 + e;
        const int n   = g >> 5;
        const int jn  = nbr[g] & (N_NODES - 1);
        float pn[12], pj[12];
        #pragma unroll
        for (int r = 0; r < 3; ++r) {
            f32x4 a = *(const f32x4*)(pos + n*12 + r*4);
            f32x4 b = *(const f32x4*)(pos + jn*12 + r*4);
            #pragma unroll
            for (int c = 0; c < 4; ++c) { pn[r*4+c] = a[c]; pj[r*4+c] = b[c]; }
        }
        float Rn[9], Rj[9];
        make_frame(pn, Rn); make_frame(pj, Rj);
        float dx = pj[3]-pn[3], dy = pj[4]-pn[4], dz = pj[5]-pn[5];
        float d = sqrtf(dx*dx + dy*dy + dz*dz + 1e-6f);
        float inv = 1.f/(d + 1e-6f);
        float ux = dx*inv, uy = dy*inv, uz = dz*inv;
        float feats[40];
        #pragma unroll
        for (int bb = 0; bb < 16; ++bb) {
            float ee = d - (22.f/15.f)*bb;
            feats[bb] = __expf(-ee*ee*0.264462809917f);
        }
        #pragma unroll
        for (int bb = 0; bb < 3; ++bb)
            feats[16+bb] = Rn[bb]*ux + Rn[3+bb]*uy + Rn[6+bb]*uz;
        #pragma unroll
        for (int bb = 0; bb < 3; ++bb)
            #pragma unroll
            for (int cc = 0; cc < 3; ++cc)
                feats[19+bb*3+cc] = Rn[bb]*Rj[cc] + Rn[3+bb]*Rj[3+cc] + Rn[6+bb]*Rj[6+cc];
        #pragma unroll
        for (int aa = 0; aa < 4; ++aa) {
            float vx = pj[aa*3+0]-pn[3], vy = pj[aa*3+1]-pn[4], vz = pj[aa*3+2]-pn[5];
            #pragma unroll
            for (int bb = 0; bb < 3; ++bb)
                feats[28+aa*3+bb] = Rn[bb]*vx + Rn[3+bb]*vy + Rn[6+bb]*vz;
        }
        char* fb = Fv + e*128;
        const int rx = (e & 7) << 4;
        if (!sub) {
            #pragma unroll
            for (int f = 0; f < 20; ++f)
                *(unsigned short*)(fb + ((2*f) ^ rx)) = hwbf(feats[f]);
        } else {
            #pragma unroll
            for (int f = 20; f < 40; ++f)
                *(unsigned short*)(fb + ((2*f) ^ rx)) = hwbf(feats[f]);
            int same = (chain[n]==chain[jn]) & (batch[n]==batch[jn]);
            int rel = resi[jn] - resi[n];
            rel = (rel < -32 ? -32 : (rel > 32 ? 32 : rel)) + 32;
            meta[e] = same ? (rel + 1) : 0;
        }
    }
    WAIT_LGKM();

    const int rxl = (lrow & 7) << 4;

    // ---- feature GEMM (K=64): accF[e][p]  (R8-proven orientation) ----
    f32x4 accF[2][8];
    #pragma unroll
    for (int ni = 0; ni < 2; ++ni)
        #pragma unroll
        for (int pb = 0; pb < 8; ++pb) accF[ni][pb] = (f32x4){0.f,0.f,0.f,0.f};
    #pragma unroll
    for (int ks = 0; ks < 2; ++ks) {
        bf16x8 a0 = *(const bf16x8*)(Fv + lrow*128       + ((16*lk + 64*ks) ^ rxl));
        bf16x8 a1 = *(const bf16x8*)(Fv + (16+lrow)*128  + ((16*lk + 64*ks) ^ rxl));
        #pragma unroll
        for (int pb = 0; pb < 8; ++pb) {
            bf16x8 b = *(const bf16x8*)(wftp_c + ((pb*2 + ks)*64 + lane)*16);
            accF[0][pb] = MFMA32(a0, b, accF[0][pb]);
            accF[1][pb] = MFMA32(a1, b, accF[1][pb]);
        }
    }
    WAIT_LGKM();   // CRITICAL: feats reads fully complete before X overwrites the region

    // ---- W_rel add (fp32) + LayerNorm (DPP reduce, in-register) -> X bf16 natural layout ----
    {
        float lnSv[8], lnBv[8];
        #pragma unroll
        for (int pb = 0; pb < 8; ++pb) {
            lnSv[pb] = ln_scale[pb*16 + lrow];
            lnBv[pb] = ln_bias [pb*16 + lrow];
        }
        #pragma unroll
        for (int ni = 0; ni < 2; ++ni) {
            #pragma unroll
            for (int i = 0; i < 4; ++i) {
                int er = ni*16 + 4*lk + i;
                int mt = meta[er];
                const float* wrel = W_rel + (mt > 0 ? (mt-1)*128 : 0);
                float sv = (mt > 0) ? 1.f : 0.f;
                float s = 0.f, ss = 0.f;
                #pragma unroll
                for (int pb = 0; pb < 8; ++pb) {
                    float x = accF[ni][pb][i] + sv * wrel[pb*16 + lrow];
                    accF[ni][pb][i] = x;
                    s += x; ss += x*x;
                }
                s  = row16_sum(s);
                ss = row16_sum(ss);
                float mu  = s * 0.0078125f;
                float var = ss * 0.0078125f - mu*mu;
                float rstd = rsqrtf(var + 1e-5f);
                char* xb = Xv + er*256;
                const int rx2 = (er & 7) << 4;
                #pragma unroll
                for (int pb = 0; pb < 8; ++pb) {
                    float xv = (accF[ni][pb][i] - mu) * rstd * lnSv[pb] + lnBv[pb];
                    *(unsigned short*)(xb + ((2*(pb*16 + lrow)) ^ rx2)) = hwbf(xv);
                }
            }
        }
    }
    WAIT_LGKM();

    // ---- X frags held in registers for the whole MLP (natural k=p order) ----
    bf16x8 bx[2][4];
    #pragma unroll
    for (int ni = 0; ni < 2; ++ni)
        #pragma unroll
        for (int ks = 0; ks < 4; ++ks)
            bx[ni][ks] = *(const bf16x8*)(Xv + (ni*16+lrow)*256 + ((16*lk + 64*ks) ^ rxl));

    // ---- MLP: 8 slices of 32 h. GEMM1 (swapped, C1[h][e]) -> gelu in-reg -> GEMM2 (K=32) ----
    f32x4 acc2[2][8];
    #pragma unroll
    for (int ni = 0; ni < 2; ++ni)
        #pragma unroll
        for (int pt = 0; pt < 8; ++pt) acc2[ni][pt] = (f32x4){0.f,0.f,0.f,0.f};

    const float C2 = -2.30220797f;     // -2*sqrt(2/pi)*log2(e)
    const float K1 = -0.10294322f;     // C2 * 0.044715
    #pragma unroll
    for (int hc = 0; hc < 8; ++hc) {
        f32x4 acc1[2][2];
        #pragma unroll
        for (int m = 0; m < 2; ++m)
            #pragma unroll
            for (int ni = 0; ni < 2; ++ni) acc1[m][ni] = (f32x4){0.f,0.f,0.f,0.f};
        #pragma unroll
        for (int ks = 0; ks < 4; ++ks) {
            bf16x8 a0 = *(const bf16x8*)(w1p_c + (((hc*2  )*4 + ks)*64 + lane)*16);
            bf16x8 a1 = *(const bf16x8*)(w1p_c + (((hc*2+1)*4 + ks)*64 + lane)*16);
            acc1[0][0] = MFMA32(a0, bx[0][ks], acc1[0][0]);
            acc1[0][1] = MFMA32(a0, bx[1][ks], acc1[0][1]);
            acc1[1][0] = MFMA32(a1, bx[0][ks], acc1[1][0]);
            acc1[1][1] = MFMA32(a1, bx[1][ks], acc1[1][1]);
        }
        f32x4 b1v[2];
        b1v[0] = *(const f32x4*)(b1 + hc*32      + 4*lk);
        b1v[1] = *(const f32x4*)(b1 + hc*32 + 16 + 4*lk);
        // gelu -> A-frag with k-slot j = m*4+i  (h_local = (j>>2)*16 + 4*lk + (j&3))
        short8v ga[2];
        #pragma unroll
        for (int m = 0; m < 2; ++m) {
            #pragma unroll
            for (int ni = 0; ni < 2; ++ni) {
                #pragma unroll
                for (int i = 0; i < 4; ++i) {
                    float x  = acc1[m][ni][i] + b1v[m][i];
                    float w  = __builtin_fmaf(K1, x*x, C2);
                    float ex = __builtin_amdgcn_exp2f(x * w);
                    ga[ni][m*4+i] = (short)hwbf(x / (1.0f + ex));
                }
            }
        }
        bf16x8 ga0 = __builtin_bit_cast(bf16x8, ga[0]);
        bf16x8 ga1 = __builtin_bit_cast(bf16x8, ga[1]);
        #pragma unroll
        for (int pt = 0; pt < 8; ++pt) {
            bf16x8 wf = *(const bf16x8*)(w2p_c + ((pt*8 + hc)*64 + lane)*16);
            acc2[0][pt] = MFMA32(ga0, wf, acc2[0][pt]);
            acc2[1][pt] = MFMA32(ga1, wf, acc2[1][pt]);
        }
    }

    // ---- epilogue: + b2, fp32 store (R8-proven layout) ----
    float b2v[8];
    #pragma unroll
    for (int pt = 0; pt < 8; ++pt) b2v[pt] = b2[pt*16 + lrow];
    #pragma unroll
    for (int ni = 0; ni < 2; ++ni) {
        #pragma unroll
        for (int pt = 0; pt < 8; ++pt) {
            #pragma unroll
            for (int i = 0; i < 4; ++i) {
                int er = ni*16 + 4*lk + i;
                out[(size_t)(edge0 + er)*128 + pt*16 + lrow] = acc2[ni][pt][i] + b2v[pt];
            }
        }
    }
}

extern "C" void kernel_launch(void* const* d_in, const int* in_sizes, int n_in,
                              void* d_out, int out_size, void* d_ws, size_t ws_size,
                              hipStream_t stream) {
    const float* pos      = (const float*)d_in[0];
    const int*   nbr      = (const int*)d_in[1];
    const int*   resi     = (const int*)d_in[2];
    const int*   chain    = (const int*)d_in[3];
    const int*   batch    = (const int*)d_in[4];
    const float* mask     = (const float*)d_in[5];
    const float* W_rel    = (const float*)d_in[6];
    const float* W_dist   = (const float*)d_in[7];
    const float* W_dir    = (const float*)d_in[8];
    const float* W_rot    = (const float*)d_in[9];
    const float* W_vec    = (const float*)d_in[10];
    const float* ln_scale = (const float*)d_in[11];
    const float* ln_bias  = (const float*)d_in[12];
    const float* W1       = (const float*)d_in[13];
    const float* b1       = (const float*)d_in[14];
    const float* W2       = (const float*)d_in[15];
    const float* b2       = (const float*)d_in[16];

    unsigned short* wftp = (unsigned short*)d_ws;         // 16 KB
    unsigned short* w1p  = wftp + 8192;                   // 64 KB
    unsigned short* w2p  = w1p + 32768;                   // 64 KB  (total 144 KB, proven)
    float* out  = (float*)d_out;
    float* outm = out + (size_t)NK * 128;

    sd_prep_weights<<<288, 256, 0, stream>>>(W1, W2, W_dist, W_dir, W_rot, W_vec,
                                             wftp, w1p, w2p);
    sd_mask_kernel<<<NK/256, 256, 0, stream>>>(nbr, mask, outm);
    sd_fused_kernel<<<NK/128, 256, 0, stream>>>(pos, nbr, resi, chain, batch, W_rel,
                                                ln_scale, ln_bias, b1, b2,
                                                (const char*)wftp, (const char*)w1p,
                                                (const char*)w2p, out);
}

// Round 13
// 396.375 us; speedup vs baseline: 1.8712x; 1.8712x over previous
//
#include <hip/hip_runtime.h>
#include <hip/hip_bf16.h>

#define N_NODES 32768
#define NK      1048576      // N*K edges

typedef __bf16 bf16x8 __attribute__((ext_vector_type(8)));
typedef float  f32x4  __attribute__((ext_vector_type(4)));
typedef short  short8v __attribute__((ext_vector_type(8)));
typedef int    int4v  __attribute__((ext_vector_type(4)));

#define WAIT_LGKM() asm volatile("s_waitcnt lgkmcnt(0)" ::: "memory")

static __device__ __forceinline__ unsigned fbits(float f) {
    union { float f; unsigned u; } v; v.f = f; return v.u;
}
static __device__ __forceinline__ unsigned short f2bf(float f) {
    unsigned u = fbits(f);
    return (unsigned short)((u + 0x7fffu + ((u >> 16) & 1u)) >> 16);   // RNE (prep only)
}
static __device__ __forceinline__ unsigned short hwbf(float f) {      // HW RNE convert
    return __builtin_bit_cast(unsigned short, __float2bfloat16(f));
}

// DPP butterfly add over the 16-lane row (no DS pipe)
template<int CTRL>
static __device__ __forceinline__ float dpp_add(float v) {
    int sw = __builtin_amdgcn_update_dpp(0, __builtin_bit_cast(int, v), CTRL, 0xf, 0xf, true);
    return v + __builtin_bit_cast(float, sw);
}
static __device__ __forceinline__ float row16_sum(float v) {
    v = dpp_add<0xB1>(v);    // quad_perm(1,0,3,2)  : xor 1
    v = dpp_add<0x4E>(v);    // quad_perm(2,3,0,1)  : xor 2
    v = dpp_add<0x141>(v);   // row_half_mirror
    v = dpp_add<0x140>(v);   // row_mirror
    return v;
}

// R[a*3+b] = e_{b}[a]  (columns e1,e2,e3)
static __device__ __forceinline__ void make_frame(const float* __restrict__ p, float* __restrict__ R) {
    float v1x = p[6]-p[3], v1y = p[7]-p[4], v1z = p[8]-p[5];
    float v2x = p[0]-p[3], v2y = p[1]-p[4], v2z = p[2]-p[5];
    float i1 = 1.f/(sqrtf(v1x*v1x+v1y*v1y+v1z*v1z)+1e-6f);
    float e1x=v1x*i1, e1y=v1y*i1, e1z=v1z*i1;
    float dt = v2x*e1x+v2y*e1y+v2z*e1z;
    float u2x=v2x-dt*e1x, u2y=v2y-dt*e1y, u2z=v2z-dt*e1z;
    float i2 = 1.f/(sqrtf(u2x*u2x+u2y*u2y+u2z*u2z)+1e-6f);
    float e2x=u2x*i2, e2y=u2y*i2, e2z=u2z*i2;
    float e3x = e1y*e2z - e1z*e2y;
    float e3y = e1z*e2x - e1x*e2z;
    float e3z = e1x*e2y - e1y*e2x;
    R[0]=e1x; R[1]=e2x; R[2]=e3x;
    R[3]=e1y; R[4]=e2y; R[5]=e3y;
    R[6]=e1z; R[7]=e2z; R[8]=e3z;
}

// ---------------- prep: pack weights into frag-linear bf16 layouts (144 KB total) ----------------
// wftp: feature-GEMM B-frags, K=64. frag(pb,ks): f = 8*(lane>>4)+j+32*ks (<40 real, else 0),
//       p = pb*16+(lane&15).                                   [8192 shorts]
// w1p : GEMM1 A-frags, natural k=p. frag(ht,ks): h = ht*16+(lane&15),
//       p = 8*(lane>>4)+j+32*ks; value = W1[p][h].             [32768 shorts]
// w2p : GEMM2 B-frags with permuted k-carriage (matches gelu A-frag):
//       frag(pt,hc): h = hc*32 + (j>>2)*16 + 4*(lane>>4) + (j&3), p = pt*16+(lane&15);
//       value = W2[h][p].                                      [32768 shorts]
__global__ void sd_prep_weights(const float* __restrict__ W1, const float* __restrict__ W2,
                                const float* __restrict__ Wd, const float* __restrict__ Wdir,
                                const float* __restrict__ Wrot, const float* __restrict__ Wvec,
                                unsigned short* __restrict__ wftp, unsigned short* __restrict__ w1p,
                                unsigned short* __restrict__ w2p) {
    int i = blockIdx.x*256 + threadIdx.x;
    if (i < 8192) {
        int fragid = i >> 9, lane = (i >> 3) & 63, j = i & 7;
        int pb = fragid >> 1, ks = fragid & 1;
        int f = 8*(lane>>4) + j + 32*ks;
        int p = pb*16 + (lane & 15);
        float v = 0.f;
        if (f < 16)       v = Wd[f*128+p];
        else if (f < 19)  v = Wdir[(f-16)*128+p];
        else if (f < 28)  v = Wrot[(f-19)*128+p];
        else if (f < 40)  v = Wvec[(f-28)*128+p];
        wftp[i] = f2bf(v);
    } else if (i < 40960) {
        int idx = i - 8192;
        int fragid = idx >> 9, lane = (idx >> 3) & 63, j = idx & 7;
        int ht = fragid >> 2, ks = fragid & 3;
        int h = ht*16 + (lane & 15);
        int p = 8*(lane>>4) + j + 32*ks;          // natural order
        w1p[idx] = f2bf(W1[p*256 + h]);
    } else if (i < 73728) {
        int idx = i - 40960;
        int fragid = idx >> 9, lane = (idx >> 3) & 63, j = idx & 7;
        int pt = fragid >> 3, hc = fragid & 7;
        int h = hc*32 + (j>>2)*16 + 4*(lane>>4) + (j&3);
        int p = pt*16 + (lane & 15);
        w2p[idx] = f2bf(W2[h*128 + p]);
    }
}

__global__ void sd_mask_kernel(const int* __restrict__ nbr, const float* __restrict__ mask,
                               float* __restrict__ outm) {
    int g = blockIdx.x*256 + threadIdx.x;
    if (g >= NK) return;
    int j = nbr[g];
    int n = g >> 5;
    float pm = mask[n] * mask[j & (N_NODES-1)] * ((j != -1) ? 1.f : 0.f);
    outm[g] = pm;
}

#define MFMA32(a,b,c) __builtin_amdgcn_mfma_f32_16x16x32_bf16((a),(b),(c),0,0,0)

// 4 independent waves per block, 32 edges each. NO barriers anywhere.
// Per-wave LDS (8 KB, OVERLAPPED): feats [32 x 128B swz] = bytes 0..4095 of the region that
// X [32 x 256B swz] later fills (0..8191). SAFETY: a WAIT_LGKM (lgkmcnt(0) + "memory"
// clobber) sits between the last feats ds_read and the first X ds_write.
// NOTE: launch_bounds kept at (256,3) — (256,4) capped the allocator at 64 VGPR and spilled
// (R12: FETCH 1.0 GB, WRITE 2.4 GB, 741 µs). LDS=33280B alone yields 4 blocks/CU in HW.
__global__ __launch_bounds__(256, 3) void sd_fused_kernel(
    const float* __restrict__ pos, const int* __restrict__ nbr,
    const int* __restrict__ resi, const int* __restrict__ chain,
    const int* __restrict__ batch, const float* __restrict__ W_rel,
    const float* __restrict__ ln_scale, const float* __restrict__ ln_bias,
    const float* __restrict__ b1, const float* __restrict__ b2,
    const char* __restrict__ wftp_c, const char* __restrict__ w1p_c,
    const char* __restrict__ w2p_c,
    float* __restrict__ out)
{
    __shared__ __align__(16) char smem[33280];
    const int t    = threadIdx.x;
    const int lane = t & 63;
    const int wid  = t >> 6;
    const int lrow = lane & 15;
    const int lk   = lane >> 4;
    const int edge0 = blockIdx.x * 128 + wid * 32;
    char* Fv = smem + wid * 8192;              // feats region (first 4 KB of wave region)
    char* Xv = Fv;                             // X region (full 8 KB, reuses feats space)
    int* meta = (int*)(smem + 32768 + wid*128);

    // ---- zero-fill feats region (tail f in [40,64) must be zero) ----
    {
        int4v z = (int4v){0,0,0,0};
        #pragma unroll
        for (int k = 0; k < 4; ++k) *(int4v*)(Fv + lane*64 + k*16) = z;
    }
    WAIT_LGKM();

    // ---- phase F: 2 lanes per edge (R8-proven scalar writes) ----
    {
        const int e   = lane >> 1;
        const int sub = lane & 1;
        const int g   = edge0 + e;
        const int n   = g >> 5;
        const int jn  = nbr[g] & (N_NODES - 1);
        float pn[12], pj[12];
        #pragma unroll
        for (int r = 0; r < 3; ++r) {
            f32x4 a = *(const f32x4*)(pos + n*12 + r*4);
            f32x4 b = *(const f32x4*)(pos + jn*12 + r*4);
            #pragma unroll
            for (int c = 0; c < 4; ++c) { pn[r*4+c] = a[c]; pj[r*4+c] = b[c]; }
        }
        float Rn[9], Rj[9];
        make_frame(pn, Rn); make_frame(pj, Rj);
        float dx = pj[3]-pn[3], dy = pj[4]-pn[4], dz = pj[5]-pn[5];
        float d = sqrtf(dx*dx + dy*dy + dz*dz + 1e-6f);
        float inv = 1.f/(d + 1e-6f);
        float ux = dx*inv, uy = dy*inv, uz = dz*inv;
        float feats[40];
        #pragma unroll
        for (int bb = 0; bb < 16; ++bb) {
            float ee = d - (22.f/15.f)*bb;
            feats[bb] = __expf(-ee*ee*0.264462809917f);
        }
        #pragma unroll
        for (int bb = 0; bb < 3; ++bb)
            feats[16+bb] = Rn[bb]*ux + Rn[3+bb]*uy + Rn[6+bb]*uz;
        #pragma unroll
        for (int bb = 0; bb < 3; ++bb)
            #pragma unroll
            for (int cc = 0; cc < 3; ++cc)
                feats[19+bb*3+cc] = Rn[bb]*Rj[cc] + Rn[3+bb]*Rj[3+cc] + Rn[6+bb]*Rj[6+cc];
        #pragma unroll
        for (int aa = 0; aa < 4; ++aa) {
            float vx = pj[aa*3+0]-pn[3], vy = pj[aa*3+1]-pn[4], vz = pj[aa*3+2]-pn[5];
            #pragma unroll
            for (int bb = 0; bb < 3; ++bb)
                feats[28+aa*3+bb] = Rn[bb]*vx + Rn[3+bb]*vy + Rn[6+bb]*vz;
        }
        char* fb = Fv + e*128;
        const int rx = (e & 7) << 4;
        if (!sub) {
            #pragma unroll
            for (int f = 0; f < 20; ++f)
                *(unsigned short*)(fb + ((2*f) ^ rx)) = hwbf(feats[f]);
        } else {
            #pragma unroll
            for (int f = 20; f < 40; ++f)
                *(unsigned short*)(fb + ((2*f) ^ rx)) = hwbf(feats[f]);
            int same = (chain[n]==chain[jn]) & (batch[n]==batch[jn]);
            int rel = resi[jn] - resi[n];
            rel = (rel < -32 ? -32 : (rel > 32 ? 32 : rel)) + 32;
            meta[e] = same ? (rel + 1) : 0;
        }
    }
    WAIT_LGKM();

    const int rxl = (lrow & 7) << 4;

    // ---- feature GEMM (K=64): accF[e][p]  (R8-proven orientation) ----
    f32x4 accF[2][8];
    #pragma unroll
    for (int ni = 0; ni < 2; ++ni)
        #pragma unroll
        for (int pb = 0; pb < 8; ++pb) accF[ni][pb] = (f32x4){0.f,0.f,0.f,0.f};
    #pragma unroll
    for (int ks = 0; ks < 2; ++ks) {
        bf16x8 a0 = *(const bf16x8*)(Fv + lrow*128       + ((16*lk + 64*ks) ^ rxl));
        bf16x8 a1 = *(const bf16x8*)(Fv + (16+lrow)*128  + ((16*lk + 64*ks) ^ rxl));
        #pragma unroll
        for (int pb = 0; pb < 8; ++pb) {
            bf16x8 b = *(const bf16x8*)(wftp_c + ((pb*2 + ks)*64 + lane)*16);
            accF[0][pb] = MFMA32(a0, b, accF[0][pb]);
            accF[1][pb] = MFMA32(a1, b, accF[1][pb]);
        }
    }
    WAIT_LGKM();   // CRITICAL: feats reads fully complete before X overwrites the region

    // ---- W_rel add (fp32) + LayerNorm (DPP reduce, in-register) -> X bf16 natural layout ----
    {
        float lnSv[8], lnBv[8];
        #pragma unroll
        for (int pb = 0; pb < 8; ++pb) {
            lnSv[pb] = ln_scale[pb*16 + lrow];
            lnBv[pb] = ln_bias [pb*16 + lrow];
        }
        #pragma unroll
        for (int ni = 0; ni < 2; ++ni) {
            #pragma unroll
            for (int i = 0; i < 4; ++i) {
                int er = ni*16 + 4*lk + i;
                int mt = meta[er];
                const float* wrel = W_rel + (mt > 0 ? (mt-1)*128 : 0);
                float sv = (mt > 0) ? 1.f : 0.f;
                float s = 0.f, ss = 0.f;
                #pragma unroll
                for (int pb = 0; pb < 8; ++pb) {
                    float x = accF[ni][pb][i] + sv * wrel[pb*16 + lrow];
                    accF[ni][pb][i] = x;
                    s += x; ss += x*x;
                }
                s  = row16_sum(s);
                ss = row16_sum(ss);
                float mu  = s * 0.0078125f;
                float var = ss * 0.0078125f - mu*mu;
                float rstd = rsqrtf(var + 1e-5f);
                char* xb = Xv + er*256;
                const int rx2 = (er & 7) << 4;
                #pragma unroll
                for (int pb = 0; pb < 8; ++pb) {
                    float xv = (accF[ni][pb][i] - mu) * rstd * lnSv[pb] + lnBv[pb];
                    *(unsigned short*)(xb + ((2*(pb*16 + lrow)) ^ rx2)) = hwbf(xv);
                }
            }
        }
    }
    WAIT_LGKM();

    // ---- X frags held in registers for the whole MLP (natural k=p order) ----
    bf16x8 bx[2][4];
    #pragma unroll
    for (int ni = 0; ni < 2; ++ni)
        #pragma unroll
        for (int ks = 0; ks < 4; ++ks)
            bx[ni][ks] = *(const bf16x8*)(Xv + (ni*16+lrow)*256 + ((16*lk + 64*ks) ^ rxl));

    // ---- MLP: 8 slices of 32 h. GEMM1 (swapped, C1[h][e]) -> gelu in-reg -> GEMM2 (K=32) ----
    f32x4 acc2[2][8];
    #pragma unroll
    for (int ni = 0; ni < 2; ++ni)
        #pragma unroll
        for (int pt = 0; pt < 8; ++pt) acc2[ni][pt] = (f32x4){0.f,0.f,0.f,0.f};

    const float C2 = -2.30220797f;     // -2*sqrt(2/pi)*log2(e)
    const float K1 = -0.10294322f;     // C2 * 0.044715
    #pragma unroll
    for (int hc = 0; hc < 8; ++hc) {
        f32x4 acc1[2][2];
        #pragma unroll
        for (int m = 0; m < 2; ++m)
            #pragma unroll
            for (int ni = 0; ni < 2; ++ni) acc1[m][ni] = (f32x4){0.f,0.f,0.f,0.f};
        #pragma unroll
        for (int ks = 0; ks < 4; ++ks) {
            bf16x8 a0 = *(const bf16x8*)(w1p_c + (((hc*2  )*4 + ks)*64 + lane)*16);
            bf16x8 a1 = *(const bf16x8*)(w1p_c + (((hc*2+1)*4 + ks)*64 + lane)*16);
            acc1[0][0] = MFMA32(a0, bx[0][ks], acc1[0][0]);
            acc1[0][1] = MFMA32(a0, bx[1][ks], acc1[0][1]);
            acc1[1][0] = MFMA32(a1, bx[0][ks], acc1[1][0]);
            acc1[1][1] = MFMA32(a1, bx[1][ks], acc1[1][1]);
        }
        f32x4 b1v[2];
        b1v[0] = *(const f32x4*)(b1 + hc*32      + 4*lk);
        b1v[1] = *(const f32x4*)(b1 + hc*32 + 16 + 4*lk);
        // gelu -> A-frag with k-slot j = m*4+i  (h_local = (j>>2)*16 + 4*lk + (j&3))
        short8v ga[2];
        #pragma unroll
        for (int m = 0; m < 2; ++m) {
            #pragma unroll
            for (int ni = 0; ni < 2; ++ni) {
                #pragma unroll
                for (int i = 0; i < 4; ++i) {
                    float x  = acc1[m][ni][i] + b1v[m][i];
                    float w  = __builtin_fmaf(K1, x*x, C2);
                    float ex = __builtin_amdgcn_exp2f(x * w);
                    ga[ni][m*4+i] = (short)hwbf(x / (1.0f + ex));
                }
            }
        }
        bf16x8 ga0 = __builtin_bit_cast(bf16x8, ga[0]);
        bf16x8 ga1 = __builtin_bit_cast(bf16x8, ga[1]);
        #pragma unroll
        for (int pt = 0; pt < 8; ++pt) {
            bf16x8 wf = *(const bf16x8*)(w2p_c + ((pt*8 + hc)*64 + lane)*16);
            acc2[0][pt] = MFMA32(ga0, wf, acc2[0][pt]);
            acc2[1][pt] = MFMA32(ga1, wf, acc2[1][pt]);
        }
    }

    // ---- epilogue: + b2, fp32 store (R8-proven layout) ----
    float b2v[8];
    #pragma unroll
    for (int pt = 0; pt < 8; ++pt) b2v[pt] = b2[pt*16 + lrow];
    #pragma unroll
    for (int ni = 0; ni < 2; ++ni) {
        #pragma unroll
        for (int pt = 0; pt < 8; ++pt) {
            #pragma unroll
            for (int i = 0; i < 4; ++i) {
                int er = ni*16 + 4*lk + i;
                out[(size_t)(edge0 + er)*128 + pt*16 + lrow] = acc2[ni][pt][i] + b2v[pt];
            }
        }
    }
}

extern "C" void kernel_launch(void* const* d_in, const int* in_sizes, int n_in,
                              void* d_out, int out_size, void* d_ws, size_t ws_size,
                              hipStream_t stream) {
    const float* pos      = (const float*)d_in[0];
    const int*   nbr      = (const int*)d_in[1];
    const int*   resi     = (const int*)d_in[2];
    const int*   chain    = (const int*)d_in[3];
    const int*   batch    = (const int*)d_in[4];
    const float* mask     = (const float*)d_in[5];
    const float* W_rel    = (const float*)d_in[6];
    const float* W_dist   = (const float*)d_in[7];
    const float* W_dir    = (const float*)d_in[8];
    const float* W_rot    = (const float*)d_in[9];
    const float* W_vec    = (const float*)d_in[10];
    const float* ln_scale = (const float*)d_in[11];
    const float* ln_bias  = (const float*)d_in[12];
    const float* W1       = (const float*)d_in[13];
    const float* b1       = (const float*)d_in[14];
    const float* W2       = (const float*)d_in[15];
    const float* b2       = (const float*)d_in[16];

    unsigned short* wftp = (unsigned short*)d_ws;         // 16 KB
    unsigned short* w1p  = wftp + 8192;                   // 64 KB
    unsigned short* w2p  = w1p + 32768;                   // 64 KB  (total 144 KB, proven)
    float* out  = (float*)d_out;
    float* outm = out + (size_t)NK * 128;

    sd_prep_weights<<<288, 256, 0, stream>>>(W1, W2, W_dist, W_dir, W_rot, W_vec,
                                             wftp, w1p, w2p);
    sd_mask_kernel<<<NK/256, 256, 0, stream>>>(nbr, mask, outm);
    sd_fused_kernel<<<NK/128, 256, 0, stream>>>(pos, nbr, resi, chain, batch, W_rel,
                                                ln_scale, ln_bias, b1, b2,
                                                (const char*)wftp, (const char*)w1p,
                                                (const char*)w2p, out);
}